// Round 2
// baseline (131.259 us; speedup 1.0000x reference)
//
#include <hip/hip_runtime.h>
#include <hip/hip_bf16.h>

typedef unsigned int u32;
typedef unsigned short u16;

#define TOKENS 512
#define OUT_F  8192
#define IN_F   4096
#define KPACK  (IN_F / 4)
#define TMB 128              // block m-tile
#define TNB 64               // block n-tile (halved: grid 512 = 2 blocks/CU)
#define BKW 128              // k per window
#define NWIN (IN_F / BKW)    // 32

typedef __attribute__((ext_vector_type(8))) short bf16x8;
typedef __attribute__((ext_vector_type(4))) float f32x4;
typedef __attribute__((ext_vector_type(16))) float f32x16;

__device__ __forceinline__ u32 pack_bf16x2(float a, float b) {
    __hip_bfloat162 h = __float22bfloat162_rn(make_float2(a, b));
    union { __hip_bfloat162 h2; u32 u; } cvt;
    cvt.h2 = h;
    return cvt.u;
}

// 2 codes (4 bits) -> 2 packed bf16 via byte-table v_perm.
// code 0 -> 0xBF80 (-1), 2 -> 0x3F80 (+1), 1/3 -> 0x0000.
__device__ __forceinline__ u32 decode_pair(u32 d) {
    u32 s = (__umul24(d, 0x808202u) & 0x06060606u) + 0x01000100u;
    return __builtin_amdgcn_perm(0x00003F80u, 0x0000BF80u, s);
}
// 16 bits (8 consecutive-k codes) at bit offset sh of w -> B fragment.
__device__ __forceinline__ bf16x8 decode_frag(u32 w, int sh) {
    union { bf16x8 v; u32 u[4]; } c;
    c.u[0] = decode_pair((w >> (sh + 0)) & 0xFu);
    c.u[1] = decode_pair((w >> (sh + 4)) & 0xFu);
    c.u[2] = decode_pair((w >> (sh + 8)) & 0xFu);
    c.u[3] = decode_pair((w >> (sh + 12)) & 0xFu);
    return c.v;
}

__device__ __forceinline__ void async_ld16(const void* g, void* l) {
    __builtin_amdgcn_global_load_lds(
        (const __attribute__((address_space(1))) u32*)g,
        (__attribute__((address_space(3))) u32*)l, 16, 0, 0);
}

// ---- pre-pass 1: X fp32 -> bf16 (row-major) ----
__global__ __launch_bounds__(256) void convert_x(const float* __restrict__ X,
                                                 u16* __restrict__ Xb) {
    int i = (blockIdx.x * 256 + threadIdx.x) * 8;
    float4 a = *(const float4*)(X + i);
    float4 b = *(const float4*)(X + i + 4);
    uint4 q;
    q.x = pack_bf16x2(a.x, a.y);
    q.y = pack_bf16x2(a.z, a.w);
    q.z = pack_bf16x2(b.x, b.y);
    q.w = pack_bf16x2(b.z, b.w);
    *(uint4*)(Xb + i) = q;
}

// ---- pre-pass 2: repack W2 -> dense 2-bit fragment-major, per-wave u32 streams (W9) ----
// W9 u32 idx = (((nb*4 + kq)*2 + nh)*NWIN + w)*64 + lane
//   nb = 64-col block (0..127), wave (kq, nh); value = 16 codes (2 u16) for
//   col = nb*64 + nh*32 + (lane&31), k = w*128 + kq*32 + ksub*16 + (lane>>5)*8 .. +7
__global__ __launch_bounds__(256) void repack_w9(const u32* __restrict__ W2,
                                                 u32* __restrict__ W9) {
    __shared__ u32 dense[128 * 32];    // 16 KB; dense[col*32 + (j ^ (col&31))]
    const int ngrp = blockIdx.x;       // 64 col-groups of 128
    const int kc   = blockIdx.y;       // 8 k-chunks of 512 codes (4 windows)
    const int t = threadIdx.x;
#pragma unroll
    for (int i = 0; i < 16; ++i) {     // phase 1: coalesced uint4 reads
        int id = t + 256 * i;
        int col = id >> 5, jq = id & 31;
        uint4 wv = *(const uint4*)(W2 + (size_t)(ngrp * 128 + col) * KPACK + kc * 128 + jq * 4);
        dense[col * 32 + (jq ^ (col & 31))] =
            (wv.x & 0xFFu) | ((wv.y & 0xFFu) << 8) | ((wv.z & 0xFFu) << 16) | ((wv.w & 0xFFu) << 24);
    }
    __syncthreads();
    const u16* sp = (const u16*)dense;
#pragma unroll
    for (int p = 0; p < 4; ++p) {      // phase 2: per-stream coalesced u32 writes
        int e = t + 256 * p;           // 0..1023
        int lane = e & 63;
        int kq = (e >> 6) & 3;
        int wp2 = (e >> 8) & 1;        // window-pair within this kc
        int nho = (e >> 9) & 1;        // which 64-col half of the 128-col group
        int h = lane >> 5;
        int c0 = nho * 64 + (lane & 31), c1 = c0 + 32;
        int nb = ngrp * 2 + nho;
#pragma unroll
        for (int ws = 0; ws < 2; ++ws) {
            int wloc = wp2 * 2 + ws;
            int w = kc * 4 + wloc;
            int j0 = wloc * 8 + kq * 2;
            u32 x0 = sp[((c0 * 32 + (j0 ^ (c0 & 31))) << 1) | h];
            u32 x1 = sp[((c0 * 32 + ((j0 + 1) ^ (c0 & 31))) << 1) | h];
            u32 y0 = sp[((c1 * 32 + (j0 ^ (c1 & 31))) << 1) | h];
            u32 y1 = sp[((c1 * 32 + ((j0 + 1) ^ (c1 & 31))) << 1) | h];
            W9[((((size_t)nb * 4 + kq) * 2 + 0) * NWIN + w) * 64 + lane] = x0 | (x1 << 16);
            W9[((((size_t)nb * 4 + kq) * 2 + 1) * NWIN + w) * 64 + lane] = y0 | (y1 << 16);
        }
    }
}

// ---- main GEMM: 128x64 block, 512 thr, 8 waves = 4 kq x 2 nh, mt=4,
//      BK=128 windows, TWO blocks/CU (the occupancy lever): 64 KB LDS,
//      64 AGPR acc + ~60 VGPR forced under 128 by __launch_bounds__(512,4).
//      Proven R0 structure: 2 LDS A-buffers + __syncthreads per window,
//      B prefetched to VGPR 2 windows ahead. ----
__global__ __launch_bounds__(512, 4) void ternary_gemm10(
    const u16* __restrict__ Xb,
    const u32* __restrict__ W9,
    const float* __restrict__ alpha,
    const float* __restrict__ bias,
    float* __restrict__ Out)
{
    __shared__ u16 As[2][TMB * BKW];   // 2 x 32 KB; epilogue reuses as reduction scratch

    const int tid  = threadIdx.x;
    const int lane = tid & 63;
    const int wave = tid >> 6;
    const int kq = wave & 3;           // k-quarter (32 of each 128-k window)
    const int nh = wave >> 2;          // n-half (32 cols)

    const int m0 = blockIdx.x * TMB;
    const int nb = blockIdx.y;
    const int n0 = nb * TNB;

    f32x16 acc[4];
#pragma unroll
    for (int mt = 0; mt < 4; ++mt)
#pragma unroll
        for (int i = 0; i < 16; ++i)
            acc[mt][i] = 0.f;

    // A staging: wave stages rows [wave*16, wave*16+16), 4 insts x 4 rows.
    // Row = 128 k = 16 chunks of 16 B; chunk c stored at slot c ^ (row&15).
    // SGPR base + small per-lane u32 offsets (register diet).
    const u16* gbase = Xb + (size_t)(m0 + wave * 16) * IN_F;   // wave-uniform
    u32 aoff[4];
    u32 lbase[4];                                              // wave-uniform
#pragma unroll
    for (int i = 0; i < 4; ++i) {
        int rr = i * 4 + (lane >> 4);
        int cd = (lane & 15) ^ (rr & 15);
        aoff[i] = rr * IN_F + cd * 8;
        lbase[i] = (wave * 16 + i * 4) * BKW;
    }

    // A-fragment LDS offsets (u16 units); mt adds +32 rows = +8192 B (imm offset)
    u32 ofsA0[2];
#pragma unroll
    for (int ks = 0; ks < 2; ++ks) {
        int row = lane & 31;
        int chunk = kq * 4 + ks * 2 + (lane >> 5);
        ofsA0[ks] = row * BKW + (chunk ^ (row & 15)) * 8;
    }

    // B: one u32 per lane per window, contiguous per-wave stream.
    const u32* wq = W9 + ((((size_t)nb * 4 + kq) * 2 + nh) * NWIN) * 64 + lane;

    u32 wcur = wq[0];
    u32 wnext = wq[64];
#pragma unroll
    for (int i = 0; i < 4; ++i) async_ld16(gbase + aoff[i], &As[0][lbase[i]]);
    __syncthreads();

    for (int w = 0; w < NWIN; ++w) {
        const int buf = w & 1;
        if (w + 1 < NWIN) {
            const int koff = (w + 1) * BKW;
#pragma unroll
            for (int i = 0; i < 4; ++i)
                async_ld16(gbase + aoff[i] + koff, &As[buf ^ 1][lbase[i]]);
        }
        u32 wnn = 0;
        if (w + 2 < NWIN) wnn = wq[(size_t)(w + 2) * 64];

        const u16* ab = As[buf];
#pragma unroll
        for (int ks = 0; ks < 2; ++ks) {
            const u16* ap = ab + ofsA0[ks];
            bf16x8 a0 = *(const bf16x8*)(ap);
            bf16x8 a1 = *(const bf16x8*)(ap + 4096);
            bf16x8 a2 = *(const bf16x8*)(ap + 8192);
            bf16x8 a3 = *(const bf16x8*)(ap + 12288);
            bf16x8 b0 = decode_frag(wcur, ks * 16);
            acc[0] = __builtin_amdgcn_mfma_f32_32x32x16_bf16(a0, b0, acc[0], 0, 0, 0);
            acc[1] = __builtin_amdgcn_mfma_f32_32x32x16_bf16(a1, b0, acc[1], 0, 0, 0);
            acc[2] = __builtin_amdgcn_mfma_f32_32x32x16_bf16(a2, b0, acc[2], 0, 0, 0);
            acc[3] = __builtin_amdgcn_mfma_f32_32x32x16_bf16(a3, b0, acc[3], 0, 0, 0);
        }
        wcur = wnext;
        wnext = wnn;
        __syncthreads();
    }

    // ---- 4-way kq reduction through LDS (3 staggered rounds, 32 KB scratch) ----
    f32x4* red = (f32x4*)As;           // need 2048 f32x4 = 32 KB (fits in As[0])
#pragma unroll 1
    for (int q = 1; q < 4; ++q) {
        if (kq == q) {
            f32x4* dst = red + nh * 1024 + lane;
#pragma unroll
            for (int mt = 0; mt < 4; ++mt)
#pragma unroll
                for (int sub = 0; sub < 4; ++sub) {
                    f32x4 v = {acc[mt][sub * 4 + 0], acc[mt][sub * 4 + 1],
                               acc[mt][sub * 4 + 2], acc[mt][sub * 4 + 3]};
                    dst[(mt * 4 + sub) * 64] = v;
                }
        }
        __syncthreads();
        if (kq == 0) {
            const f32x4* src = red + nh * 1024 + lane;
#pragma unroll
            for (int mt = 0; mt < 4; ++mt)
#pragma unroll
                for (int sub = 0; sub < 4; ++sub) {
                    f32x4 v = src[(mt * 4 + sub) * 64];
#pragma unroll
                    for (int i = 0; i < 4; ++i)
                        acc[mt][sub * 4 + i] += v[i];
                }
        }
        __syncthreads();
    }

    // ---- epilogue (kq==0 waves): alpha*acc + bias ----
    if (kq == 0) {
        int ncol = n0 + nh * 32 + (lane & 31);
        float av = alpha[ncol];
        float bv = bias[ncol];
#pragma unroll
        for (int mt = 0; mt < 4; ++mt) {
#pragma unroll
            for (int r = 0; r < 16; ++r) {
                int row = m0 + mt * 32 + (r & 3) + 8 * (r >> 2) + 4 * (lane >> 5);
                Out[(size_t)row * OUT_F + ncol] = acc[mt][r] * av + bv;
            }
        }
    }
}

// ---- naive fallback (workspace too small; correctness only) ----
__global__ void ternary_naive(const float* __restrict__ X, const u32* __restrict__ W2,
                              const float* __restrict__ alpha, const float* __restrict__ bias,
                              float* __restrict__ Out) {
    int o  = blockIdx.x * 64 + (threadIdx.x & 63);
    int tk = blockIdx.y * 4 + (threadIdx.x >> 6);
    const float* x = X + (size_t)tk * IN_F;
    const u32* w = W2 + (size_t)o * KPACK;
    float s = 0.f;
    for (int d = 0; d < KPACK; ++d) {
        u32 b = w[d] & 0xFFu;
        const float* xp = x + d * 4;
#pragma unroll
        for (int j = 0; j < 4; ++j) {
            u32 c = (b >> (2 * j)) & 3u;
            float wv = (c == 2u) ? 1.f : ((c == 0u) ? -1.f : 0.f);
            s += xp[j] * wv;
        }
    }
    Out[(size_t)tk * OUT_F + o] = s * alpha[o] + bias[o];
}

extern "C" void kernel_launch(void* const* d_in, const int* in_sizes, int n_in,
                              void* d_out, int out_size, void* d_ws, size_t ws_size,
                              hipStream_t stream) {
    const float* x = (const float*)d_in[0];
    const u32* w2 = (const u32*)d_in[1];
    const float* alpha = (const float*)d_in[2];
    const float* bias  = (const float*)d_in[3];
    float* out = (float*)d_out;

    const size_t xb_bytes = (size_t)TOKENS * IN_F * sizeof(u16);   // 4 MB
    const size_t w9_bytes = (size_t)OUT_F * IN_F / 4;              // 8 MB

    if (ws_size >= xb_bytes + w9_bytes) {
        u16* xb = (u16*)d_ws;
        u32* w9 = (u32*)((char*)d_ws + xb_bytes);
        convert_x<<<(TOKENS * IN_F) / (256 * 8), 256, 0, stream>>>(x, xb);
        repack_w9<<<dim3(64, 8), 256, 0, stream>>>(w2, w9);
        ternary_gemm10<<<dim3(TOKENS / TMB, OUT_F / TNB), 512, 0, stream>>>(xb, w9, alpha, bias, out);
    } else {
        ternary_naive<<<dim3(OUT_F / 64, TOKENS / 4), 256, 0, stream>>>(x, w2, alpha, bias, out);
    }
}

// Round 3
// 125.199 us; speedup vs baseline: 1.0484x; 1.0484x over previous
//
#include <hip/hip_runtime.h>
#include <hip/hip_bf16.h>

typedef unsigned int u32;
typedef unsigned short u16;

#define TOKENS 512
#define OUT_F  8192
#define IN_F   4096
#define KPACK  (IN_F / 4)
#define TMB 128              // block m-tile
#define TNB 128              // block n-tile
#define BKW 128              // k per window
#define NWIN (IN_F / BKW)    // 32

typedef __attribute__((ext_vector_type(8))) short bf16x8;
typedef __attribute__((ext_vector_type(4))) float f32x4;
typedef __attribute__((ext_vector_type(16))) float f32x16;

__device__ __forceinline__ u32 pack_bf16x2(float a, float b) {
    __hip_bfloat162 h = __float22bfloat162_rn(make_float2(a, b));
    union { __hip_bfloat162 h2; u32 u; } cvt;
    cvt.h2 = h;
    return cvt.u;
}

// 2 codes (4 bits) -> 2 packed bf16 via byte-table v_perm.
// code 0 -> 0xBF80 (-1), 2 -> 0x3F80 (+1), 1/3 -> 0x0000.
__device__ __forceinline__ u32 decode_pair(u32 d) {
    u32 s = (__umul24(d, 0x808202u) & 0x06060606u) + 0x01000100u;
    return __builtin_amdgcn_perm(0x00003F80u, 0x0000BF80u, s);
}
// 16 bits (8 consecutive-k codes) at bit offset sh of w -> B fragment.
__device__ __forceinline__ bf16x8 decode_frag(u32 w, int sh) {
    union { bf16x8 v; u32 u[4]; } c;
    c.u[0] = decode_pair((w >> (sh + 0)) & 0xFu);
    c.u[1] = decode_pair((w >> (sh + 4)) & 0xFu);
    c.u[2] = decode_pair((w >> (sh + 8)) & 0xFu);
    c.u[3] = decode_pair((w >> (sh + 12)) & 0xFu);
    return c.v;
}

__device__ __forceinline__ void async_ld16(const void* g, void* l) {
    __builtin_amdgcn_global_load_lds(
        (const __attribute__((address_space(1))) u32*)g,
        (__attribute__((address_space(3))) u32*)l, 16, 0, 0);
}

// B prefetch via inline asm: keeps a deterministic FIFO position in the
// vmcnt queue (a compiler-scheduled load could drift and break the manual
// counts). Dest VGPRs are valid only after the matching s_waitcnt.
__device__ __forceinline__ void async_b(const uint2* g, uint2& dst) {
    asm volatile("global_load_dwordx2 %0, %1, off"
                 : "=v"(dst) : "v"(g) : "memory");
}

#define VMW(N) asm volatile("s_waitcnt vmcnt(" #N ")" ::: "memory")

// ---- pre-pass 1: X fp32 -> bf16 (row-major) ----
__global__ __launch_bounds__(256) void convert_x(const float* __restrict__ X,
                                                 u16* __restrict__ Xb) {
    int i = (blockIdx.x * 256 + threadIdx.x) * 8;
    float4 a = *(const float4*)(X + i);
    float4 b = *(const float4*)(X + i + 4);
    uint4 q;
    q.x = pack_bf16x2(a.x, a.y);
    q.y = pack_bf16x2(a.z, a.w);
    q.z = pack_bf16x2(b.x, b.y);
    q.w = pack_bf16x2(b.z, b.w);
    *(uint4*)(Xb + i) = q;
}

// ---- pre-pass 2: repack W2 -> dense 2-bit fragment-major (W7, R0 layout) ----
// W7 uint2 idx = (((ngrp*2+nh)*32 + w)*4 + kq)*64 + lane
//  .x u16[ksub] = 8 codes for col = ngrp*128 + nh*64 +      (lane&31),
//                 k = w*128 + kq*32 + ksub*16 + (lane>>5)*8 .. +7
//  .y = same for col +32
__global__ __launch_bounds__(256) void repack_w7(const u32* __restrict__ W2,
                                                 uint2* __restrict__ W7) {
    __shared__ u32 dense[128 * 32];    // 16 KB; dense[col*32 + (j ^ (col&31))]
    const int ngrp = blockIdx.x;       // 64 col-groups of 128
    const int kc   = blockIdx.y;       // 8 k-chunks of 512 codes
    const int t = threadIdx.x;
#pragma unroll
    for (int i = 0; i < 16; ++i) {     // phase 1: coalesced uint4 reads
        int id = t + 256 * i;
        int col = id >> 5, jq = id & 31;
        uint4 wv = *(const uint4*)(W2 + (size_t)(ngrp * 128 + col) * KPACK + kc * 128 + jq * 4);
        dense[col * 32 + (jq ^ (col & 31))] =
            (wv.x & 0xFFu) | ((wv.y & 0xFFu) << 8) | ((wv.z & 0xFFu) << 16) | ((wv.w & 0xFFu) << 24);
    }
    __syncthreads();
    const u16* sp = (const u16*)dense;
#pragma unroll
    for (int p = 0; p < 8; ++p) {      // phase 2: coalesced uint2 writes
        int e = t + 256 * p;           // 0..2047
        int lane = e & 63;
        int kq = (e >> 6) & 3;
        int wloc = (e >> 8) & 3;
        int nh = (e >> 10) & 1;
        int h = lane >> 5;
        int c0 = nh * 64 + (lane & 31), c1 = c0 + 32;
        int j0 = wloc * 8 + kq * 2;
        u32 x0 = sp[((c0 * 32 + (j0 ^ (c0 & 31))) << 1) | h];
        u32 x1 = sp[((c0 * 32 + ((j0 + 1) ^ (c0 & 31))) << 1) | h];
        u32 y0 = sp[((c1 * 32 + (j0 ^ (c1 & 31))) << 1) | h];
        u32 y1 = sp[((c1 * 32 + ((j0 + 1) ^ (c1 & 31))) << 1) | h];
        uint2 o;
        o.x = x0 | (x1 << 16);
        o.y = y0 | (y1 << 16);
        int w = kc * 4 + wloc;
        W7[(((size_t)(ngrp * 2 + nh) * 32 + w) * 4 + kq) * 64 + lane] = o;
    }
}

// ---- main GEMM: R0 geometry (128x128 block, 512 thr, 8 waves = 4 kq x 2 nh,
//      mt=4, BKW=128 windows, 1 block/CU) + counted-vmcnt pipeline:
//      4 A window-buffers (128 KB), depth-2 prefetch issued POST-barrier,
//      steady-state s_waitcnt vmcnt(5) (never 0 in the loop), B in VGPRs via
//      asm loads for deterministic FIFO counting. ----
__global__ __launch_bounds__(512, 2) void ternary_gemm11(
    const u16* __restrict__ Xb,
    const uint2* __restrict__ W7,
    const float* __restrict__ alpha,
    const float* __restrict__ bias,
    float* __restrict__ Out)
{
    __shared__ u16 As[4][TMB * BKW];   // 4 x 32 KB; epilogue reuses [0..64KB) as scratch

    const int tid  = threadIdx.x;
    const int lane = tid & 63;
    const int wave = tid >> 6;
    const int kq = wave & 3;           // k-quarter (32 of each 128-k window)
    const int nh = wave >> 2;          // n-half (64 cols)

    const int m0 = blockIdx.x * TMB;
    const int ngrp = blockIdx.y;
    const int n0 = ngrp * TNB;

    f32x16 acc[4][2];
#pragma unroll
    for (int mt = 0; mt < 4; ++mt)
#pragma unroll
        for (int nt = 0; nt < 2; ++nt)
#pragma unroll
            for (int i = 0; i < 16; ++i)
                acc[mt][nt][i] = 0.f;

    // A staging: wave stages rows [wave*16, wave*16+16), 4 insts x 4 rows.
    // Row = 128 k = 16 chunks of 16 B; chunk c stored at slot c ^ (row&15).
    const u16* ga[4];
    u32 lbase[4];
#pragma unroll
    for (int i = 0; i < 4; ++i) {
        int rbase = wave * 16 + i * 4;
        int row = rbase + (lane >> 4);
        int cd = (lane & 15) ^ (row & 15);
        ga[i] = Xb + (size_t)(m0 + row) * IN_F + cd * 8;
        lbase[i] = rbase * BKW;
    }

    // A-fragment LDS offsets (u16 units); row&15 == lane&15 since mt*32 ≡ 0 mod 16
    int ofsA[4][2];
#pragma unroll
    for (int mt = 0; mt < 4; ++mt)
#pragma unroll
        for (int ks = 0; ks < 2; ++ks) {
            int row = mt * 32 + (lane & 31);
            int chunk = kq * 4 + ks * 2 + (lane >> 5);
            ofsA[mt][ks] = row * BKW + ((chunk ^ (row & 15))) * 8;
        }

    const uint2* wp = W7 + ((size_t)(ngrp * 2 + nh) * NWIN * 4 + kq) * 64 + lane;

    auto issueA = [&](int w) {
        u16* d = As[w & 3];
        const int koff = w * BKW;
#pragma unroll
        for (int i = 0; i < 4; ++i)
            async_ld16(ga[i] + koff, d + lbase[i]);
    };

    auto window_compute = [&](int buf, uint2 bq) {
        const u16* ab = As[buf];
#pragma unroll
        for (int ks = 0; ks < 2; ++ks) {
            bf16x8 a0 = *(const bf16x8*)(ab + ofsA[0][ks]);
            bf16x8 a1 = *(const bf16x8*)(ab + ofsA[1][ks]);
            bf16x8 a2 = *(const bf16x8*)(ab + ofsA[2][ks]);
            bf16x8 a3 = *(const bf16x8*)(ab + ofsA[3][ks]);
            bf16x8 b0 = decode_frag(bq.x, ks * 16);
            bf16x8 b1 = decode_frag(bq.y, ks * 16);
            acc[0][0] = __builtin_amdgcn_mfma_f32_32x32x16_bf16(a0, b0, acc[0][0], 0, 0, 0);
            acc[1][0] = __builtin_amdgcn_mfma_f32_32x32x16_bf16(a1, b0, acc[1][0], 0, 0, 0);
            acc[2][0] = __builtin_amdgcn_mfma_f32_32x32x16_bf16(a2, b0, acc[2][0], 0, 0, 0);
            acc[3][0] = __builtin_amdgcn_mfma_f32_32x32x16_bf16(a3, b0, acc[3][0], 0, 0, 0);
            acc[0][1] = __builtin_amdgcn_mfma_f32_32x32x16_bf16(a0, b1, acc[0][1], 0, 0, 0);
            acc[1][1] = __builtin_amdgcn_mfma_f32_32x32x16_bf16(a1, b1, acc[1][1], 0, 0, 0);
            acc[2][1] = __builtin_amdgcn_mfma_f32_32x32x16_bf16(a2, b1, acc[2][1], 0, 0, 0);
            acc[3][1] = __builtin_amdgcn_mfma_f32_32x32x16_bf16(a3, b1, acc[3][1], 0, 0, 0);
        }
    };

    // Prologue, exact FIFO order: B(0), A(0)x4, B(1), A(1)x4  -> 10 in flight.
    uint2 bqE, bqO;
    async_b(wp, bqE);
    issueA(0);
    async_b(wp + 256, bqO);
    issueA(1);

    // Window body: wait vmcnt(5) -> oldest 5 (= B(w), A(w)x4) retired; barrier;
    // sched_barrier(0) fences the VALU decode against hoisting above the wait
    // (rule: asm waitcnt + register-only consumer); compute; then issue w+2
    // POST-barrier (its buffer's readers were at w-2, two barriers back).
#pragma unroll 1
    for (int p = 0; p < (NWIN - 2) / 2; ++p) {   // windows 0..29
        const int w = 2 * p;
        VMW(5);
        __builtin_amdgcn_s_barrier();
        __builtin_amdgcn_sched_barrier(0);
        window_compute(w & 3, bqE);
        async_b(wp + (size_t)(w + 2) * 256, bqE);
        issueA(w + 2);

        VMW(5);
        __builtin_amdgcn_s_barrier();
        __builtin_amdgcn_sched_barrier(0);
        window_compute((w + 1) & 3, bqO);
        async_b(wp + (size_t)(w + 3) * 256, bqO);
        issueA(w + 3);
    }
    // w = 30: outstanding = B(30),A(30)x4,B(31),A(31)x4 = 10 -> wait oldest 5.
    VMW(5);
    __builtin_amdgcn_s_barrier();
    __builtin_amdgcn_sched_barrier(0);
    window_compute(30 & 3, bqE);
    // w = 31: final drain.
    VMW(0);
    __builtin_amdgcn_s_barrier();
    __builtin_amdgcn_sched_barrier(0);
    window_compute(31 & 3, bqO);

    // ---- 4-way kq reduction through LDS (3 staggered rounds, 64 KB scratch) ----
    // Scratch = As[0..64KB) = buffers 0,1: last read at windows 28/29, separated
    // from here by the w=30/31 barriers; all DMAs drained by the final vmcnt(0)
    // which every wave executed before the last barrier.
    f32x4* red = (f32x4*)As;           // 4096 f32x4 = 64 KB
#pragma unroll 1
    for (int q = 1; q < 4; ++q) {
        if (kq == q) {
            f32x4* dst = red + nh * 2048 + lane;
#pragma unroll
            for (int mt = 0; mt < 4; ++mt)
#pragma unroll
                for (int nt = 0; nt < 2; ++nt)
#pragma unroll
                    for (int sub = 0; sub < 4; ++sub) {
                        f32x4 v = {acc[mt][nt][sub * 4 + 0], acc[mt][nt][sub * 4 + 1],
                                   acc[mt][nt][sub * 4 + 2], acc[mt][nt][sub * 4 + 3]};
                        dst[(mt * 8 + nt * 4 + sub) * 64] = v;
                    }
        }
        __syncthreads();
        if (kq == 0) {
            const f32x4* src = red + nh * 2048 + lane;
#pragma unroll
            for (int mt = 0; mt < 4; ++mt)
#pragma unroll
                for (int nt = 0; nt < 2; ++nt)
#pragma unroll
                    for (int sub = 0; sub < 4; ++sub) {
                        f32x4 v = src[(mt * 8 + nt * 4 + sub) * 64];
#pragma unroll
                        for (int i = 0; i < 4; ++i)
                            acc[mt][nt][sub * 4 + i] += v[i];
                    }
        }
        __syncthreads();
    }

    // ---- epilogue (kq==0 waves): alpha*acc + bias ----
    if (kq == 0) {
#pragma unroll
        for (int nt = 0; nt < 2; ++nt) {
            int ncol = n0 + nh * 64 + nt * 32 + (lane & 31);
            float av = alpha[ncol];
            float bv = bias[ncol];
#pragma unroll
            for (int mt = 0; mt < 4; ++mt) {
#pragma unroll
                for (int r = 0; r < 16; ++r) {
                    int row = m0 + mt * 32 + (r & 3) + 8 * (r >> 2) + 4 * (lane >> 5);
                    Out[(size_t)row * OUT_F + ncol] = acc[mt][nt][r] * av + bv;
                }
            }
        }
    }
}

// ---- naive fallback (workspace too small; correctness only) ----
__global__ void ternary_naive(const float* __restrict__ X, const u32* __restrict__ W2,
                              const float* __restrict__ alpha, const float* __restrict__ bias,
                              float* __restrict__ Out) {
    int o  = blockIdx.x * 64 + (threadIdx.x & 63);
    int tk = blockIdx.y * 4 + (threadIdx.x >> 6);
    const float* x = X + (size_t)tk * IN_F;
    const u32* w = W2 + (size_t)o * KPACK;
    float s = 0.f;
    for (int d = 0; d < KPACK; ++d) {
        u32 b = w[d] & 0xFFu;
        const float* xp = x + d * 4;
#pragma unroll
        for (int j = 0; j < 4; ++j) {
            u32 c = (b >> (2 * j)) & 3u;
            float wv = (c == 2u) ? 1.f : ((c == 0u) ? -1.f : 0.f);
            s += xp[j] * wv;
        }
    }
    Out[(size_t)tk * OUT_F + o] = s * alpha[o] + bias[o];
}

extern "C" void kernel_launch(void* const* d_in, const int* in_sizes, int n_in,
                              void* d_out, int out_size, void* d_ws, size_t ws_size,
                              hipStream_t stream) {
    const float* x = (const float*)d_in[0];
    const u32* w2 = (const u32*)d_in[1];
    const float* alpha = (const float*)d_in[2];
    const float* bias  = (const float*)d_in[3];
    float* out = (float*)d_out;

    const size_t xb_bytes = (size_t)TOKENS * IN_F * sizeof(u16);   // 4 MB
    const size_t w7_bytes = (size_t)OUT_F * IN_F / 4;              // 8 MB

    if (ws_size >= xb_bytes + w7_bytes) {
        u16* xb = (u16*)d_ws;
        uint2* w7 = (uint2*)((char*)d_ws + xb_bytes);
        convert_x<<<(TOKENS * IN_F) / (256 * 8), 256, 0, stream>>>(x, xb);
        repack_w7<<<dim3(64, 8), 256, 0, stream>>>(w2, w7);
        ternary_gemm11<<<dim3(TOKENS / TMB, OUT_F / TNB), 512, 0, stream>>>(xb, w7, alpha, bias, out);
    } else {
        ternary_naive<<<dim3(OUT_F / 64, TOKENS / 4), 256, 0, stream>>>(x, w2, alpha, bias, out);
    }
}